// Round 11
// baseline (362.671 us; speedup 1.0000x reference)
//
#include <hip/hip_runtime.h>

// LSTM round 11: 2 waves/SIMD, zero transc redundancy. B=8192, T=512, IN=5, H=32.
// 1024 blocks x 128 thr -> 4 blocks/CU -> uniform 2 waves/SIMD. Each wave is an
// independent 4-batch in-wave recurrence (f16 frame): cols = 4 batches dup-4,
// lane (col,kg): bloc=col&3, q=col>>2 -> jsel=q&1, rp=q>>1; owns cells
// j0=16jsel+4kg+2rp and j0+1. 16 MFMA/step (chain-2 + pipelined chain-1 for t+1).
// No LDS tiles, no barriers; bh rebuilt with 4 bpermute/wave.

typedef __attribute__((ext_vector_type(8))) _Float16 half8;
typedef __attribute__((ext_vector_type(4))) float f32x4;
typedef __attribute__((ext_vector_type(4))) unsigned int u32x4;

static constexpr int BB  = 8192;
static constexpr int TT  = 512;
static constexpr int NIN = 5;
static constexpr int HH  = 32;

__device__ __forceinline__ unsigned short f16b(float f) {
    _Float16 h = (_Float16)f;                       // RNE
    return __builtin_bit_cast(unsigned short, h);
}
__device__ __forceinline__ float fast_sigmoid(float x) {
    float e = __builtin_amdgcn_exp2f(-1.4426950408889634f * x);
    return __builtin_amdgcn_rcpf(1.0f + e);
}
__device__ __forceinline__ float fast_tanh(float x) {
    float e = __builtin_amdgcn_exp2f(2.8853900817779268f * x);
    return 1.0f - 2.0f * __builtin_amdgcn_rcpf(1.0f + e);
}

__global__ __launch_bounds__(128) void lstm_f16x2(
    const float* __restrict__ x,     // [B, T, 5]
    const float* __restrict__ W_ih,  // [128, 5]
    const float* __restrict__ W_hh,  // [128, 32]
    const float* __restrict__ b_ih,  // [128]
    const float* __restrict__ b_hh,  // [128]
    const float* __restrict__ W_fc,  // [1, 32]
    const float* __restrict__ b_fc,  // [1]
    float* __restrict__ out)         // [B]
{
    const int tid  = threadIdx.x;
    const int w    = tid >> 6;       // wave 0/1 (independent 4-batch groups)
    const int lane = tid & 63;
    const int col  = lane & 15;
    const int kg   = lane >> 4;
    const int bloc = col & 3;        // batch within group (cols dup 4x)
    const int q    = col >> 2;
    const int jsel = q & 1;          // j bit-4
    const int rp   = q >> 1;         // acc reg pair
    const int base = blockIdx.x * 8 + 4 * w;
    const int j0   = 16 * jsel + 4 * kg + 2 * rp;   // cells j0, j0+1

    // ---- A-fragments (loop-invariant). Tile t4: gate rows gr=16*t4+col,
    // k=kg*8+e. Ahh: W_hh@f16. Ax (kg0 only): slots0-4=W_ih@f16,
    // slot5=bias_hi, slot6=bias_lo, slot7=0; kg1-3 zero. ----
    half8 Ahh[8], Ax[8];
#pragma unroll
    for (int t4 = 0; t4 < 8; ++t4) {
        const int gr = 16 * t4 + col;
#pragma unroll
        for (int e = 0; e < 8; ++e)
            Ahh[t4][e] = (_Float16)W_hh[gr * HH + kg * 8 + e];
        half8 v;
#pragma unroll
        for (int e = 0; e < 8; ++e) v[e] = (_Float16)0.f;
        if (kg == 0) {
#pragma unroll
            for (int e = 0; e < NIN; ++e) v[e] = (_Float16)W_ih[gr * NIN + e];
            float bias = b_ih[gr] + b_hh[gr];
            _Float16 bh_ = (_Float16)bias;
            v[5] = bh_;
            v[6] = (_Float16)(bias - (float)bh_);
        }
        Ax[t4] = v;
    }

    // ---- bh bpermute sources: word m = {h[J], h[J+1]}, J = 8kg+2m, of my batch.
    // Owner of cell pair (J, J+1): jsel'=J>>4, kg'=(J&15)>>2, rp'=(J>>1)&1;
    // src = 16*kg' + 4*(2*rp'+jsel') + bloc. ----
    int src0, src1, src2, src3;
    {
        int s[4];
#pragma unroll
        for (int m = 0; m < 4; ++m) {
            const int J  = 8 * kg + 2 * m;
            const int js = J >> 4;
            const int kp = (J & 15) >> 2;
            const int rq = (J >> 1) & 1;
            s[m] = 16 * kp + 4 * (2 * rq + js) + bloc;
        }
        src0 = s[0]; src1 = s[1]; src2 = s[2]; src3 = s[3];
    }

    const bool xk = (kg == 0);

    // ---- x stream: own batch row (16 lanes share addr -> broadcast) ----
    const float* px = x + (size_t)(base + bloc) * TT * NIN;
    float x0 = px[0], x1 = px[1], x2 = px[2], x3 = px[3], x4 = px[4];

    unsigned int bh0 = 0, bh1 = 0, bh2 = 0, bh3 = 0;   // h^T frag (h=0)
    float cc0 = 0.f, cc1 = 0.f, hh0 = 0.f, hh1 = 0.f;
    const f32x4 z = {0.f, 0.f, 0.f, 0.f};

    auto make_bx = [&](float v0, float v1, float v2, float v3, float v4) -> half8 {
        unsigned w0 = (unsigned)f16b(v0) | ((unsigned)f16b(v1) << 16);
        unsigned w1 = (unsigned)f16b(v2) | ((unsigned)f16b(v3) << 16);
        unsigned w2 = (unsigned)f16b(v4) | (0x3C00u << 16);   // slot5 = 1.0
        unsigned w3 = 0x00003C00u;                            // slot6 = 1.0
        u32x4 u = {xk ? w0 : 0u, xk ? w1 : 0u, xk ? w2 : 0u, xk ? w3 : 0u};
        return __builtin_bit_cast(half8, u);
    };

    // ---- prologue: chain-1 for t=0 ----
    f32x4 accN[8];
    {
        half8 bx0 = make_bx(x0, x1, x2, x3, x4);
#pragma unroll
        for (int t4 = 0; t4 < 8; ++t4)
            accN[t4] = __builtin_amdgcn_mfma_f32_16x16x32_f16(Ax[t4], bx0, z, 0, 0, 0);
    }

#pragma unroll 1
    for (int t = 0; t < TT; ++t) {
        // (1) prefetch x(t+1)
        const size_t off = (size_t)((t + 1 < TT) ? (t + 1) : t) * NIN;
        float n0 = px[off + 0], n1 = px[off + 1], n2 = px[off + 2],
              n3 = px[off + 3], n4 = px[off + 4];

        // (2) chain-2: acc = Ahh*bh + accN
        u32x4 bhu = {bh0, bh1, bh2, bh3};
        half8 bh = __builtin_bit_cast(half8, bhu);
        f32x4 acc[8];
#pragma unroll
        for (int t4 = 0; t4 < 8; ++t4)
            acc[t4] = __builtin_amdgcn_mfma_f32_16x16x32_f16(Ahh[t4], bh, accN[t4], 0, 0, 0);

        // (3) chain-1 for t+1 (independent; fills cell-phase matrix idle)
        half8 bxn = make_bx(n0, n1, n2, n3, n4);
#pragma unroll
        for (int t4 = 0; t4 < 8; ++t4)
            accN[t4] = __builtin_amdgcn_mfma_f32_16x16x32_f16(Ax[t4], bxn, z, 0, 0, 0);

        // (4) gate select: gate G of cell d at acc[2G+jsel][2rp+d]
        float g0[4], g1[4];
#pragma unroll
        for (int G = 0; G < 4; ++G) {
            const f32x4 tA = acc[2 * G], tB = acc[2 * G + 1];
            float a0 = rp ? tA[2] : tA[0];
            float a1 = rp ? tA[3] : tA[1];
            float b0v = rp ? tB[2] : tB[0];
            float b1v = rp ? tB[3] : tB[1];
            g0[G] = jsel ? b0v : a0;
            g1[G] = jsel ? b1v : a1;
        }

        // (5) two cells
        {
            float iv = fast_sigmoid(g0[0]);
            float fv = fast_sigmoid(g0[1]);
            float gv = fast_tanh(g0[2]);
            float ov = fast_sigmoid(g0[3]);
            cc0 = fmaf(fv, cc0, iv * gv);
            hh0 = ov * fast_tanh(cc0);
        }
        {
            float iv = fast_sigmoid(g1[0]);
            float fv = fast_sigmoid(g1[1]);
            float gv = fast_tanh(g1[2]);
            float ov = fast_sigmoid(g1[3]);
            cc1 = fmaf(fv, cc1, iv * gv);
            hh1 = ov * fast_tanh(cc1);
        }

        // (6) publish pair; rebuild bh via 4 bpermute
        unsigned int p = (unsigned)f16b(hh0) | ((unsigned)f16b(hh1) << 16);
        bh0 = (unsigned)__shfl((int)p, src0, 64);
        bh1 = (unsigned)__shfl((int)p, src1, 64);
        bh2 = (unsigned)__shfl((int)p, src2, 64);
        bh3 = (unsigned)__shfl((int)p, src3, 64);

        x0 = n0; x1 = n1; x2 = n2; x3 = n3; x4 = n4;
    }

    // ---- head: out[b] = sum_j h[b][j]*W_fc[j] + b_fc ----
    float v = hh0 * W_fc[j0] + hh1 * W_fc[j0 + 1];
    v += __shfl_xor(v, 4);    // combine q bits
    v += __shfl_xor(v, 8);
    v += __shfl_xor(v, 16);   // combine kg bits
    v += __shfl_xor(v, 32);
    if (lane < 4) out[base + lane] = v + b_fc[0];
}

extern "C" void kernel_launch(void* const* d_in, const int* in_sizes, int n_in,
                              void* d_out, int out_size, void* d_ws, size_t ws_size,
                              hipStream_t stream) {
    const float* x    = (const float*)d_in[0];
    const float* W_ih = (const float*)d_in[1];
    const float* W_hh = (const float*)d_in[2];
    const float* b_ih = (const float*)d_in[3];
    const float* b_hh = (const float*)d_in[4];
    const float* W_fc = (const float*)d_in[5];
    const float* b_fc = (const float*)d_in[6];
    float* out = (float*)d_out;

    lstm_f16x2<<<dim3(BB / 8), dim3(128), 0, stream>>>(
        x, W_ih, W_hh, b_ih, b_hh, W_fc, b_fc, out);
}

// Round 12
// 280.095 us; speedup vs baseline: 1.2948x; 1.2948x over previous
//
#include <hip/hip_runtime.h>

// LSTM round 12: R10 frame (8 batches/wave, 1024 waves = 1/SIMD, f16 MFMA,
// pipelined chain-1, no LDS tiles, no barriers) + QUAD-PAIRED RECIPROCALS:
// all sigmoid/tanh denominators share rcps (4 gate-dens -> 1 rcp per cell;
// 4 tanh(c) dens -> 1 rcp across cells). Transc/lane-step: 40 -> 25.
// exp2 args clamped at 30 (saturation-exact, overflow-proof products).

typedef __attribute__((ext_vector_type(8))) _Float16 half8;
typedef __attribute__((ext_vector_type(4))) float f32x4;
typedef __attribute__((ext_vector_type(4))) unsigned int u32x4;

static constexpr int BB  = 8192;
static constexpr int TT  = 512;
static constexpr int NIN = 5;
static constexpr int HH  = 32;
static constexpr float K1 = 1.4426950408889634f;   // log2(e)
static constexpr float K2 = 2.8853900817779268f;   // 2*log2(e)

__device__ __forceinline__ unsigned short f16b(float f) {
    _Float16 h = (_Float16)f;                       // RNE
    return __builtin_bit_cast(unsigned short, h);
}

__global__ __launch_bounds__(64) void lstm_qr(
    const float* __restrict__ x,     // [B, T, 5]
    const float* __restrict__ W_ih,  // [128, 5]
    const float* __restrict__ W_hh,  // [128, 32]
    const float* __restrict__ b_ih,  // [128]
    const float* __restrict__ b_hh,  // [128]
    const float* __restrict__ W_fc,  // [1, 32]
    const float* __restrict__ b_fc,  // [1]
    float* __restrict__ out)         // [B]
{
    const int lane = threadIdx.x & 63;
    const int col  = lane & 15;      // batch (dup x2)
    const int kg   = lane >> 4;      // k-group
    const int b0   = blockIdx.x * 8;
    const int bloc = col & 7;
    const bool jlow = (col < 8);
    const int jbase = 4 * kg + (jlow ? 0 : 16);

    // ---- A-fragments (loop-invariant). Tile t4: gate rows gr=16*t4+col,
    // k=kg*8+e. Ahh: W_hh@f16. Ax (kg0 only): slots0-4=W_ih@f16,
    // slot5=bias_hi, slot6=bias_lo, slot7=0; kg1-3 zero.
    half8 Ahh[8], Ax[8];
#pragma unroll
    for (int t4 = 0; t4 < 8; ++t4) {
        const int gr = 16 * t4 + col;
#pragma unroll
        for (int e = 0; e < 8; ++e)
            Ahh[t4][e] = (_Float16)W_hh[gr * HH + kg * 8 + e];
        half8 v;
#pragma unroll
        for (int e = 0; e < 8; ++e) v[e] = (_Float16)0.f;
        if (kg == 0) {
#pragma unroll
            for (int e = 0; e < NIN; ++e) v[e] = (_Float16)W_ih[gr * NIN + e];
            float bias = b_ih[gr] + b_hh[gr];
            _Float16 bh_ = (_Float16)bias;
            v[5] = bh_;
            v[6] = (_Float16)(bias - (float)bh_);
        }
        Ax[t4] = v;
    }

    // ---- bh shuffle sources (R5/R10-verified mapping) ----
    const int srcA = 32 * (kg & 1) + bloc + 8 * (kg >> 1);
    const int srcB = srcA + 16;

    const bool xk = (kg == 0);

    // ---- x stream: per-lane loads of own batch row (8-lane broadcast) ----
    const float* px = x + (size_t)(b0 + bloc) * TT * NIN;
    float x0 = px[0], x1 = px[1], x2 = px[2], x3 = px[3], x4 = px[4];

    unsigned int bh0 = 0, bh1 = 0, bh2 = 0, bh3 = 0;   // h^T frag (h=0)
    float c0 = 0.f, c1 = 0.f, c2 = 0.f, c3 = 0.f;
    float h0 = 0.f, h1 = 0.f, h2 = 0.f, h3 = 0.f;
    const f32x4 z = {0.f, 0.f, 0.f, 0.f};

    auto make_bx = [&](float v0, float v1, float v2, float v3, float v4) -> half8 {
        unsigned w0 = (unsigned)f16b(v0) | ((unsigned)f16b(v1) << 16);
        unsigned w1 = (unsigned)f16b(v2) | ((unsigned)f16b(v3) << 16);
        unsigned w2 = (unsigned)f16b(v4) | (0x3C00u << 16);   // slot5 = 1.0
        unsigned w3 = 0x00003C00u;                            // slot6 = 1.0
        u32x4 u = {xk ? w0 : 0u, xk ? w1 : 0u, xk ? w2 : 0u, xk ? w3 : 0u};
        return __builtin_bit_cast(half8, u);
    };

    // ---- prologue: chain-1 for t=0 ----
    f32x4 accN[8];
    {
        half8 bx0 = make_bx(x0, x1, x2, x3, x4);
#pragma unroll
        for (int t4 = 0; t4 < 8; ++t4)
            accN[t4] = __builtin_amdgcn_mfma_f32_16x16x32_f16(Ax[t4], bx0, z, 0, 0, 0);
    }

#pragma unroll 1
    for (int t = 0; t < TT; ++t) {
        // (1) prefetch x(t+1)
        const size_t off = (size_t)((t + 1 < TT) ? (t + 1) : t) * NIN;
        float n0 = px[off + 0], n1 = px[off + 1], n2 = px[off + 2],
              n3 = px[off + 3], n4 = px[off + 4];

        // (2) chain-2: acc = Ahh*bh + accN
        u32x4 bhu = {bh0, bh1, bh2, bh3};
        half8 bh = __builtin_bit_cast(half8, bhu);
        f32x4 acc[8];
#pragma unroll
        for (int t4 = 0; t4 < 8; ++t4)
            acc[t4] = __builtin_amdgcn_mfma_f32_16x16x32_f16(Ahh[t4], bh, accN[t4], 0, 0, 0);

        // (3) chain-1 for t+1 (independent; fills cell-phase matrix idle)
        half8 bxn = make_bx(n0, n1, n2, n3, n4);
#pragma unroll
        for (int t4 = 0; t4 < 8; ++t4)
            accN[t4] = __builtin_amdgcn_mfma_f32_16x16x32_f16(Ax[t4], bxn, z, 0, 0, 0);

        // (4) 4 cells, quad-paired reciprocals.
        //  sigmoid(x) = 1/(1+exp2(min(-K1 x,30)))
        //  tanh(x)    = 1-2/(1+exp2(min(K2 x,30)))
        float ov[4], dc[4];
#pragma unroll
        for (int r = 0; r < 4; ++r) {
            float gi = jlow ? acc[0][r] : acc[1][r];
            float gf = jlow ? acc[2][r] : acc[3][r];
            float gg = jlow ? acc[4][r] : acc[5][r];
            float go = jlow ? acc[6][r] : acc[7][r];

            float ei = __builtin_amdgcn_exp2f(fminf(-K1 * gi, 30.f));
            float ef = __builtin_amdgcn_exp2f(fminf(-K1 * gf, 30.f));
            float eg = __builtin_amdgcn_exp2f(fminf( K2 * gg, 30.f));
            float eo = __builtin_amdgcn_exp2f(fminf(-K1 * go, 30.f));
            float di = 1.f + ei, df = 1.f + ef, dg = 1.f + eg, dq = 1.f + eo;

            float p01 = di * df, p23 = dg * dq;
            float rr = __builtin_amdgcn_rcpf(p01 * p23);
            float iv = (df * p23) * rr;               // 1/di
            float fv = (di * p23) * rr;               // 1/df
            float ginv = (p01 * dq) * rr;             // 1/dg
            float oinv = (p01 * dg) * rr;             // 1/dq
            float gv = fmaf(-2.f, ginv, 1.f);         // tanh(gg)
            ov[r] = oinv;                             // sigmoid(go)

            float cc = (r == 0 ? c0 : r == 1 ? c1 : r == 2 ? c2 : c3);
            cc = fmaf(fv, cc, iv * gv);
            if (r == 0) c0 = cc; else if (r == 1) c1 = cc;
            else if (r == 2) c2 = cc; else c3 = cc;

            float ec = __builtin_amdgcn_exp2f(fminf(K2 * cc, 30.f));
            dc[r] = 1.f + ec;                          // tanh(c) den, rcp deferred
        }
        {   // (4b) cross-cell quad rcp for tanh(c)
            float q01 = dc[0] * dc[1], q23 = dc[2] * dc[3];
            float r2 = __builtin_amdgcn_rcpf(q01 * q23);
            float i0 = (dc[1] * q23) * r2;
            float i1 = (dc[0] * q23) * r2;
            float i2 = (q01 * dc[3]) * r2;
            float i3 = (q01 * dc[2]) * r2;
            h0 = ov[0] * fmaf(-2.f, i0, 1.f);
            h1 = ov[1] * fmaf(-2.f, i1, 1.f);
            h2 = ov[2] * fmaf(-2.f, i2, 1.f);
            h3 = ov[3] * fmaf(-2.f, i3, 1.f);
        }

        // (5) pack h -> f16 pairs; rebuild bh for t+1 (4 shfl, R5 mapping)
        unsigned int p0 = (unsigned)f16b(h0) | ((unsigned)f16b(h1) << 16);
        unsigned int p1 = (unsigned)f16b(h2) | ((unsigned)f16b(h3) << 16);
        bh0 = (unsigned)__shfl((int)p0, srcA, 64);
        bh1 = (unsigned)__shfl((int)p1, srcA, 64);
        bh2 = (unsigned)__shfl((int)p0, srcB, 64);
        bh3 = (unsigned)__shfl((int)p1, srcB, 64);

        x0 = n0; x1 = n1; x2 = n2; x3 = n3; x4 = n4;
    }

    // ---- head: out[b] = sum_j h[b][j]*W_fc[j] + b_fc ----
    float v = h0 * W_fc[jbase + 0] + h1 * W_fc[jbase + 1]
            + h2 * W_fc[jbase + 2] + h3 * W_fc[jbase + 3];
    v += __shfl_xor(v, 8);
    v += __shfl_xor(v, 16);
    v += __shfl_xor(v, 32);
    if (lane < 8) out[b0 + lane] = v + b_fc[0];
}

extern "C" void kernel_launch(void* const* d_in, const int* in_sizes, int n_in,
                              void* d_out, int out_size, void* d_ws, size_t ws_size,
                              hipStream_t stream) {
    const float* x    = (const float*)d_in[0];
    const float* W_ih = (const float*)d_in[1];
    const float* W_hh = (const float*)d_in[2];
    const float* b_ih = (const float*)d_in[3];
    const float* b_hh = (const float*)d_in[4];
    const float* W_fc = (const float*)d_in[5];
    const float* b_fc = (const float*)d_in[6];
    float* out = (float*)d_out;

    lstm_qr<<<dim3(BB / 8), dim3(64), 0, stream>>>(
        x, W_ih, W_hh, b_ih, b_hh, W_fc, b_fc, out);
}